// Round 9
// baseline (57327.924 us; speedup 1.0000x reference)
//
#include <hip/hip_runtime.h>
#include <math.h>

// ESN recurrence: x_t = tanh(w_in*u_t + W x_{t-1}); out[t-washout] = c . x_t
// R9: R8 data-embedded-epoch scheme + two fixes and one probe:
//  (1) parallel-retry polling: each sweep re-issues ALL stale pair loads
//      concurrently (R8 had a per-i dependent retry chain = 8 serial RTTs).
//  (2) producer x stores via atomic_exchange (executes AT the far unit ->
//      no store-buffer/writeback visibility lag, if that was the floor).
//  (3) esn_probe_sync (runs LAST, after out is final; reuses part region):
//      per iter = store 8 pairs + poll 2048 pairs, same mechanism as main.
//      Its time = headline - esn_run row; /8192 = pure sync floor per step.

#define H_   2048
#define RPB  8          // rows per block
#define NBLK 256
typedef unsigned long long ull;
// ws layout (float idx):
//   ull  [0,4096)       x pair buffers (= float [0,8192))
//   float [8192,10240)  c (scatter of w_out by mask)
//   float [10240, 10240+T*256)  part (per-step per-block partials)
//   probe (after reduce): pairs reuse float [10240, 18432)

__global__ void esn_zero(float* __restrict__ p, int n)
{
    int i = blockIdx.x * blockDim.x + threadIdx.x;
    int stride = gridDim.x * blockDim.x;
    for (; i < n; i += stride) p[i] = 0.0f;
}

__global__ __launch_bounds__(1024) void esn_scatter_c(const int* __restrict__ mask,
                                                      const float* __restrict__ w_out,
                                                      float* __restrict__ ws_f, int H)
{
    float* c = ws_f + 8192;
    for (int i = threadIdx.x; i < H; i += blockDim.x)
        atomicAdd(&c[mask[i]], w_out[i]);
}

__global__ __launch_bounds__(256) void esn_run(const float* __restrict__ u,
                                               const float* __restrict__ w_res,
                                               const float* __restrict__ w_in,
                                               float* __restrict__ out,
                                               float* __restrict__ ws_f,
                                               int T, int washout, int use_part)
{
    __shared__ float Wlds[RPB * H_];   // 64 KB
    __shared__ float xs[H_];
    __shared__ float psum[4];

    const int tid  = threadIdx.x;
    const int wave = tid >> 6;
    const int lane = tid & 63;
    const int bid  = blockIdx.x;
    const int r0 = 2 * wave, r1 = 2 * wave + 1;
    const int grow0 = bid * RPB + r0, grow1 = bid * RPB + r1;

    {
        const float4* src = (const float4*)(w_res + (size_t)bid * RPB * H_);
        float4* dst = (float4*)Wlds;
        for (int i = tid; i < RPB * H_ / 4; i += 256) dst[i] = src[i];
    }
    float win0 = 0.f, win1 = 0.f, c0 = 0.f, c1 = 0.f;
    if (lane == 0) {
        win0 = w_in[grow0]; win1 = w_in[grow1];
        c0 = ws_f[8192 + grow0]; c1 = ws_f[8192 + grow1];
    }

    ull* pairs = (ull*)ws_f;
    float* part = ws_f + 10240;

    const float4* w0p = (const float4*)(Wlds + r0 * H_);
    const float4* w1p = (const float4*)(Wlds + r1 * H_);
    const float4* xs4 = (const float4*)xs;

    float u_next = u[0];
    __syncthreads();   // Wlds ready

    for (int k = 0; k < T; ++k) {
        const ull* sp = pairs + (k & 1) * H_;
        ull*       dp = pairs + ((k + 1) & 1) * H_;
        float uk = u_next;
        if (k + 1 < T) u_next = u[k + 1];

        // ---- stage x_k: batch load, then PARALLEL-retry sweeps ----
        ull pv[8];
#pragma unroll
        for (int i = 0; i < 8; ++i)
            pv[i] = __hip_atomic_load(sp + (i << 8) + tid, __ATOMIC_RELAXED,
                                      __HIP_MEMORY_SCOPE_AGENT);
        {
            int spins = 0;
            for (;;) {
                unsigned pend = 0;
#pragma unroll
                for (int i = 0; i < 8; ++i)
                    if ((unsigned)(pv[i] >> 32) != (unsigned)k) {
                        pv[i] = __hip_atomic_load(sp + (i << 8) + tid,
                                                  __ATOMIC_RELAXED,
                                                  __HIP_MEMORY_SCOPE_AGENT);
                        pend = 1;
                    }
                if (!pend) break;           // all fresh as of last check
                if (++spins > 500000) break; // failsafe
            }
        }
#pragma unroll
        for (int i = 0; i < 8; ++i)
            xs[(i << 8) + tid] = __uint_as_float((unsigned)pv[i]);
        __syncthreads();

        // ---- dot: wave owns rows r0,r1 ----
        float4 a0 = {0.f,0.f,0.f,0.f}, a1 = {0.f,0.f,0.f,0.f};
#pragma unroll
        for (int c = 0; c < 8; ++c) {
            float4 xv  = xs4[c * 64 + lane];
            float4 wv0 = w0p[c * 64 + lane];
            float4 wv1 = w1p[c * 64 + lane];
            a0.x = fmaf(wv0.x, xv.x, a0.x); a0.y = fmaf(wv0.y, xv.y, a0.y);
            a0.z = fmaf(wv0.z, xv.z, a0.z); a0.w = fmaf(wv0.w, xv.w, a0.w);
            a1.x = fmaf(wv1.x, xv.x, a1.x); a1.y = fmaf(wv1.y, xv.y, a1.y);
            a1.z = fmaf(wv1.z, xv.z, a1.z); a1.w = fmaf(wv1.w, xv.w, a1.w);
        }
        float s0 = (a0.x + a0.y) + (a0.z + a0.w);
        float s1 = (a1.x + a1.y) + (a1.z + a1.w);
#pragma unroll
        for (int d = 1; d < 64; d <<= 1) {
            s0 += __shfl_xor(s0, d);
            s1 += __shfl_xor(s1, d);
        }

        if (lane == 0) {
            float z0 = fmaf(win0, uk, s0);
            float z1 = fmaf(win1, uk, s1);
            z0 = fminf(fmaxf(z0, -15.f), 15.f);
            z1 = fminf(fmaxf(z1, -15.f), 15.f);
            float e0 = __expf(2.f * z0), e1 = __expf(2.f * z1);
            float t0 = (e0 - 1.f) / (e0 + 1.f), t1 = (e1 - 1.f) / (e1 + 1.f);
            ull p0 = ((ull)(unsigned)(k + 1) << 32) | (ull)__float_as_uint(t0);
            ull p1 = ((ull)(unsigned)(k + 1) << 32) | (ull)__float_as_uint(t1);
            // exchange: commits at the far unit (no writeback lag)
            (void)__hip_atomic_exchange(dp + grow0, p0, __ATOMIC_RELAXED,
                                        __HIP_MEMORY_SCOPE_AGENT);
            (void)__hip_atomic_exchange(dp + grow1, p1, __ATOMIC_RELAXED,
                                        __HIP_MEMORY_SCOPE_AGENT);
            psum[wave] = c0 * t0 + c1 * t1;
        }
        __syncthreads();   // psum ready; xs reads done (safe to restage)

        if (tid == 0) {
            float pw = (psum[0] + psum[1]) + (psum[2] + psum[3]);
            if (use_part) part[(size_t)k * NBLK + bid] = pw;
            else if (k >= washout) atomicAdd(&out[k - washout], pw);
        }
    }
}

__global__ __launch_bounds__(256) void esn_reduce(const float* __restrict__ part,
                                                  float* __restrict__ out,
                                                  int out_size, int washout)
{
    int wv = threadIdx.x >> 6, lane = threadIdx.x & 63;
    int t = blockIdx.x * 4 + wv;
    if (t >= out_size) return;
    const float4* p = (const float4*)(part + (size_t)(t + washout) * NBLK);
    float4 v = p[lane];
    float s = (v.x + v.y) + (v.z + v.w);
#pragma unroll
    for (int d = 1; d < 64; d <<= 1) s += __shfl_xor(s, d);
    if (lane == 0) out[t] = s;
}

// ---- probe: pure sync floor (store 8 pairs + poll 2048), same mechanism ----
__global__ __launch_bounds__(64) void esn_probe_sync(float* __restrict__ ws_f, int iters)
{
    ull* pairs = (ull*)(ws_f + 10240);   // reuses part region (after reduce)
    const int lane = threadIdx.x;
    const int bid  = blockIdx.x;
    int broken = 0;
    for (int k = 0; k < iters; ++k) {
        ull* dp = pairs + ((k + 1) & 1) * H_;
        ull tagv = ((ull)(unsigned)(k + 1) << 32);
        if (lane < RPB)
            (void)__hip_atomic_exchange(dp + bid * RPB + lane, tagv,
                                        __ATOMIC_RELAXED, __HIP_MEMORY_SCOPE_AGENT);
        if (!broken) {
            ull pv[32];
#pragma unroll
            for (int i = 0; i < 32; ++i)
                pv[i] = __hip_atomic_load(dp + i * 64 + lane, __ATOMIC_RELAXED,
                                          __HIP_MEMORY_SCOPE_AGENT);
            unsigned tg = (unsigned)(k + 1);
            int spins = 0;
            for (;;) {
                unsigned pend = 0;
#pragma unroll
                for (int i = 0; i < 32; ++i)
                    if ((unsigned)(pv[i] >> 32) != tg) {
                        pv[i] = __hip_atomic_load(dp + i * 64 + lane,
                                                  __ATOMIC_RELAXED,
                                                  __HIP_MEMORY_SCOPE_AGENT);
                        pend = 1;
                    }
                if (!pend) break;
                if (++spins > 50000) { broken = 1; break; }
            }
        }
        __syncthreads();
    }
}

extern "C" void kernel_launch(void* const* d_in, const int* in_sizes, int n_in,
                              void* d_out, int out_size, void* d_ws, size_t ws_size,
                              hipStream_t stream)
{
    const float* u     = (const float*)d_in[0];
    const float* w_res = (const float*)d_in[1];
    const float* w_in  = (const float*)d_in[2];
    const float* w_out = (const float*)d_in[3];
    const int*   mask  = (const int*)d_in[4];
    int T = in_sizes[0];
    int H = in_sizes[2];
    int washout = T - out_size;
    float* out  = (float*)d_out;
    float* ws_f = (float*)d_ws;

    size_t need = (size_t)(10240 + (size_t)T * NBLK) * 4;
    int use_part = (ws_size >= need) ? 1 : 0;

    hipLaunchKernelGGL(esn_zero, dim3(64), dim3(256), 0, stream, ws_f, 10240);
    if (!use_part)
        hipLaunchKernelGGL(esn_zero, dim3(32), dim3(256), 0, stream, out, out_size);
    hipLaunchKernelGGL(esn_scatter_c, dim3(1), dim3(1024), 0, stream, mask, w_out, ws_f, H);

    void* args[] = { (void*)&u, (void*)&w_res, (void*)&w_in, (void*)&out,
                     (void*)&ws_f, (void*)&T, (void*)&washout, (void*)&use_part };
    hipError_t e = hipLaunchCooperativeKernel((const void*)esn_run,
                                              dim3(NBLK), dim3(256),
                                              args, 0, stream);
    if (e != hipSuccess) {
        hipLaunchKernelGGL(esn_run, dim3(NBLK), dim3(256), 0, stream,
                           u, w_res, w_in, out, ws_f, T, washout, use_part);
    }
    if (use_part)
        hipLaunchKernelGGL(esn_reduce, dim3((out_size + 3) / 4), dim3(256), 0, stream,
                           ws_f + 10240, out, out_size, washout);

    // ---- probe runs LAST (out already final); reuses part region ----
    if (use_part) {
        hipLaunchKernelGGL(esn_zero, dim3(64), dim3(256), 0, stream, ws_f + 10240, 8192);
        int iters = 8192;
        void* pargs[] = { (void*)&ws_f, (void*)&iters };
        hipError_t ep = hipLaunchCooperativeKernel((const void*)esn_probe_sync,
                                                   dim3(NBLK), dim3(64), pargs, 0, stream);
        if (ep != hipSuccess)
            hipLaunchKernelGGL(esn_probe_sync, dim3(NBLK), dim3(64), 0, stream, ws_f, iters);
    }
}

// Round 10
// 38020.761 us; speedup vs baseline: 1.5078x; 1.5078x over previous
//
#include <hip/hip_runtime.h>
#include <math.h>

// ESN recurrence: x_t = tanh(w_in*u_t + W x_{t-1}); out[t-washout] = c . x_t
// R10: chunked poll+compute. R9 probe showed pure sync (no compute) is SLOWER
// than the full loop -> the floor is sweep turnaround (a sweep re-checks only
// after ALL its loads drain), not store->visibility latency. Now the step is
// 8 chunks of 256 pairs; each thread owns ONE pair per chunk (1-load retry
// sweeps), per-chunk partial dot overlaps the in-flight loads of later
// chunks. Probe dropped (it cost ~24ms of the R9 headline). tanh on lanes
// 0/1 in parallel. Pair scheme, exchange stores, plain part stores kept.

#define H_   2048
#define RPB  8          // rows per block
#define NBLK 256
typedef unsigned long long ull;
// ws layout (float idx):
//   ull  [0,4096)       x pair buffers (= float [0,8192))
//   float [8192,10240)  c (scatter of w_out by mask)
//   float [10240, 10240+T*256)  part (per-step per-block partials)

__global__ void esn_zero(float* __restrict__ p, int n)
{
    int i = blockIdx.x * blockDim.x + threadIdx.x;
    int stride = gridDim.x * blockDim.x;
    for (; i < n; i += stride) p[i] = 0.0f;
}

__global__ __launch_bounds__(1024) void esn_scatter_c(const int* __restrict__ mask,
                                                      const float* __restrict__ w_out,
                                                      float* __restrict__ ws_f, int H)
{
    float* c = ws_f + 8192;
    for (int i = threadIdx.x; i < H; i += blockDim.x)
        atomicAdd(&c[mask[i]], w_out[i]);
}

__global__ __launch_bounds__(256) void esn_run(const float* __restrict__ u,
                                               const float* __restrict__ w_res,
                                               const float* __restrict__ w_in,
                                               float* __restrict__ out,
                                               float* __restrict__ ws_f,
                                               int T, int washout, int use_part)
{
    __shared__ float Wlds[RPB * H_];   // 64 KB
    __shared__ float xs[H_];
    __shared__ float psum[4];

    const int tid  = threadIdx.x;
    const int wave = tid >> 6;
    const int lane = tid & 63;
    const int bid  = blockIdx.x;
    const int r0 = 2 * wave;
    const int grow0 = bid * RPB + r0;   // wave's first row; lane 0/1 handle r0/r0+1

    {
        const float4* src = (const float4*)(w_res + (size_t)bid * RPB * H_);
        float4* dst = (float4*)Wlds;
        for (int i = tid; i < RPB * H_ / 4; i += 256) dst[i] = src[i];
    }
    // per-lane scalars: lanes 0,1 own rows grow0, grow0+1
    float win_l = 0.f, c_l = 0.f;
    if (lane < 2) {
        win_l = w_in[grow0 + lane];
        c_l   = ws_f[8192 + grow0 + lane];
    }

    ull* pairs = (ull*)ws_f;
    float* part = ws_f + 10240;

    const float4* w0p = (const float4*)(Wlds + (r0)     * H_);
    const float4* w1p = (const float4*)(Wlds + (r0 + 1) * H_);
    const float4* xs4 = (const float4*)xs;

    float u_next = u[0];
    __syncthreads();   // Wlds ready

    for (int k = 0; k < T; ++k) {
        const ull* sp = pairs + (k & 1) * H_;
        ull*       dp = pairs + ((k + 1) & 1) * H_;
        float uk = u_next;
        if (k + 1 < T) u_next = u[k + 1];

        // ---- issue all 8 chunk loads upfront (one pair per thread per chunk) ----
        ull pv[8];
#pragma unroll
        for (int i = 0; i < 8; ++i)
            pv[i] = __hip_atomic_load(sp + (i << 8) + tid, __ATOMIC_RELAXED,
                                      __HIP_MEMORY_SCOPE_AGENT);

        // ---- chunked: wait own pair -> stage chunk -> partial dot ----
        float4 a0 = {0.f,0.f,0.f,0.f}, a1 = {0.f,0.f,0.f,0.f};
#pragma unroll
        for (int c = 0; c < 8; ++c) {
            int spins = 0;
            while ((unsigned)(pv[c] >> 32) != (unsigned)k) {   // 1-load retry sweep
                pv[c] = __hip_atomic_load(sp + (c << 8) + tid, __ATOMIC_RELAXED,
                                          __HIP_MEMORY_SCOPE_AGENT);
                if (++spins > 2000000) break;   // failsafe
            }
            xs[(c << 8) + tid] = __uint_as_float((unsigned)pv[c]);
            __syncthreads();
            float4 xv  = xs4[(c << 6) + lane];
            float4 wv0 = w0p[(c << 6) + lane];
            float4 wv1 = w1p[(c << 6) + lane];
            a0.x = fmaf(wv0.x, xv.x, a0.x); a0.y = fmaf(wv0.y, xv.y, a0.y);
            a0.z = fmaf(wv0.z, xv.z, a0.z); a0.w = fmaf(wv0.w, xv.w, a0.w);
            a1.x = fmaf(wv1.x, xv.x, a1.x); a1.y = fmaf(wv1.y, xv.y, a1.y);
            a1.z = fmaf(wv1.z, xv.z, a1.z); a1.w = fmaf(wv1.w, xv.w, a1.w);
        }
        float s0 = (a0.x + a0.y) + (a0.z + a0.w);
        float s1 = (a1.x + a1.y) + (a1.z + a1.w);
#pragma unroll
        for (int d = 1; d < 64; d <<= 1) {
            s0 += __shfl_xor(s0, d);
            s1 += __shfl_xor(s1, d);
        }

        // ---- tanh + store: lanes 0 and 1 in parallel (rows r0, r0+1) ----
        if (lane < 2) {
            float z = fmaf(win_l, uk, (lane == 0) ? s0 : s1);
            z = fminf(fmaxf(z, -15.f), 15.f);
            float e = __expf(2.f * z);
            float t = (e - 1.f) / (e + 1.f);
            ull p = ((ull)(unsigned)(k + 1) << 32) | (ull)__float_as_uint(t);
            (void)__hip_atomic_exchange(dp + grow0 + lane, p, __ATOMIC_RELAXED,
                                        __HIP_MEMORY_SCOPE_AGENT);
            float pr = c_l * t;
            pr += __shfl_xor(pr, 1);
            if (lane == 0) psum[wave] = pr;
        }
        __syncthreads();

        if (tid == 0) {
            float pw = (psum[0] + psum[1]) + (psum[2] + psum[3]);
            if (use_part) part[(size_t)k * NBLK + bid] = pw;
            else if (k >= washout) atomicAdd(&out[k - washout], pw);
        }
    }
}

__global__ __launch_bounds__(256) void esn_reduce(const float* __restrict__ part,
                                                  float* __restrict__ out,
                                                  int out_size, int washout)
{
    int wv = threadIdx.x >> 6, lane = threadIdx.x & 63;
    int t = blockIdx.x * 4 + wv;
    if (t >= out_size) return;
    const float4* p = (const float4*)(part + (size_t)(t + washout) * NBLK);
    float4 v = p[lane];
    float s = (v.x + v.y) + (v.z + v.w);
#pragma unroll
    for (int d = 1; d < 64; d <<= 1) s += __shfl_xor(s, d);
    if (lane == 0) out[t] = s;
}

extern "C" void kernel_launch(void* const* d_in, const int* in_sizes, int n_in,
                              void* d_out, int out_size, void* d_ws, size_t ws_size,
                              hipStream_t stream)
{
    const float* u     = (const float*)d_in[0];
    const float* w_res = (const float*)d_in[1];
    const float* w_in  = (const float*)d_in[2];
    const float* w_out = (const float*)d_in[3];
    const int*   mask  = (const int*)d_in[4];
    int T = in_sizes[0];
    int H = in_sizes[2];
    int washout = T - out_size;
    float* out  = (float*)d_out;
    float* ws_f = (float*)d_ws;

    size_t need = (size_t)(10240 + (size_t)T * NBLK) * 4;
    int use_part = (ws_size >= need) ? 1 : 0;

    hipLaunchKernelGGL(esn_zero, dim3(64), dim3(256), 0, stream, ws_f, 10240);
    if (!use_part)
        hipLaunchKernelGGL(esn_zero, dim3(32), dim3(256), 0, stream, out, out_size);
    hipLaunchKernelGGL(esn_scatter_c, dim3(1), dim3(1024), 0, stream, mask, w_out, ws_f, H);

    void* args[] = { (void*)&u, (void*)&w_res, (void*)&w_in, (void*)&out,
                     (void*)&ws_f, (void*)&T, (void*)&washout, (void*)&use_part };
    hipError_t e = hipLaunchCooperativeKernel((const void*)esn_run,
                                              dim3(NBLK), dim3(256),
                                              args, 0, stream);
    if (e != hipSuccess) {
        hipLaunchKernelGGL(esn_run, dim3(NBLK), dim3(256), 0, stream,
                           u, w_res, w_in, out, ws_f, T, washout, use_part);
    }
    if (use_part)
        hipLaunchKernelGGL(esn_reduce, dim3((out_size + 3) / 4), dim3(256), 0, stream,
                           ws_f + 10240, out, out_size, washout);
}